// Round 4
// baseline (111.387 us; speedup 1.0000x reference)
//
#include <hip/hip_runtime.h>
#include <stdint.h>

#define NDIM 64
#define KPOS 32
#define KNEG 64

// ---------------- Kernel 1: Zq = u8(sigmoid(P)*255), L_deg = MSE(Z@W_d,deg) -
__global__ __launch_bounds__(256) void pe_sig_deg_kernel(
    const float* __restrict__ P,
    const float* __restrict__ Wd,
    const float* __restrict__ deg,
    uint8_t* __restrict__ Zq,
    float* __restrict__ out,
    int N) {
  const int lane = threadIdx.x & 63;
  const int wid  = threadIdx.x >> 6;
  const int nwaves = (gridDim.x * blockDim.x) >> 6;
  int gw = (blockIdx.x * blockDim.x + threadIdx.x) >> 6;

  const float wd = Wd[lane];
  float acc = 0.f;
  for (int i = gw; i < N; i += nwaves) {
    float p = P[(unsigned)i * NDIM + lane];
    float z = 1.f / (1.f + __expf(-p));
    Zq[((unsigned)i << 6) | lane] = (uint8_t)(z * 255.f + 0.5f);
    float dot = z * wd;                        // exact f32 path for L_deg
    #pragma unroll
    for (int off = 32; off; off >>= 1) dot += __shfl_xor(dot, off);
    float d = dot - deg[i];
    acc += d * d;                              // uniform across lanes
  }
  __shared__ float sacc[4];
  if (lane == 0) sacc[wid] = acc;
  __syncthreads();
  if (threadIdx.x == 0) {
    atomicAdd(out + 2, (sacc[0] + sacc[1] + sacc[2] + sacc[3]) * (1.0f / (float)N));
  }
}

// ---------------- u8 SAD helpers -------------------------------------------
__device__ __forceinline__ unsigned sad16(uint4 a, uint4 b, unsigned acc) {
  acc = __builtin_amdgcn_sad_u8(a.x, b.x, acc);
  acc = __builtin_amdgcn_sad_u8(a.y, b.y, acc);
  acc = __builtin_amdgcn_sad_u8(a.z, b.z, acc);
  acc = __builtin_amdgcn_sad_u8(a.w, b.w, acc);
  return acc;
}

struct Idx { int p0, p1, n0, n1, n2, n3, q0, q1, m0, m1, m2, m3; };

__device__ __forceinline__ Idx load_idx(
    const int* __restrict__ pos, const int* __restrict__ neg,
    const int* __restrict__ dpos, const int* __restrict__ dneg,
    unsigned i, int q) {
  Idx d;
  const int* pr = pos  + i * KPOS;
  const int* nr = neg  + i * KNEG;
  const int* qr = dpos + i * KPOS;
  const int* mr = dneg + i * KNEG;
  d.p0 = pr[q]; d.p1 = pr[16 + q];
  d.n0 = nr[q]; d.n1 = nr[16 + q]; d.n2 = nr[32 + q]; d.n3 = nr[48 + q];
  d.q0 = qr[q]; d.q1 = qr[16 + q];
  d.m0 = mr[q]; d.m1 = mr[16 + q]; d.m2 = mr[32 + q]; d.m3 = mr[48 + q];
  return d;
}

// ---------------- Kernel 2: both contrast losses ---------------------------
__global__ __launch_bounds__(256) void pe_contrast_kernel(
    const uint8_t* __restrict__ Zq,
    const int* __restrict__ pos_idx,
    const int* __restrict__ neg_idx,
    const int* __restrict__ dpos_idx,
    const int* __restrict__ dneg_idx,
    float* __restrict__ out,
    int N) {
  const int lane = threadIdx.x & 63;
  const int q = lane >> 2, c = lane & 3;
  const int wid  = threadIdx.x >> 6;
  const int nwaves = (gridDim.x * blockDim.x) >> 6;
  const int gw = (blockIdx.x * blockDim.x + threadIdx.x) >> 6;

  const unsigned coff = (unsigned)c << 4;        // 0,16,32,48 within row
  #define ZROW(j) (*(const uint4*)(Zq + ((((unsigned)(j)) << 6) | coff)))

  float l1 = 0.f, l2 = 0.f;
  unsigned pa1 = 0u, pa2 = 0u;
  const float S = 1.4426950408889634f / 255.f;   // log2(e)/255

  int i = gw;
  Idx cur;
  if (i < N) cur = load_idx(pos_idx, neg_idx, dpos_idx, dneg_idx, (unsigned)i, q);
  while (i < N) {
    // ---- issue ALL gathers for this node up front (13 x 16B) ----
    const uint4 zi  = ZROW(i);
    const uint4 rp0 = ZROW(cur.p0), rp1 = ZROW(cur.p1);
    const uint4 rn0 = ZROW(cur.n0), rn1 = ZROW(cur.n1);
    const uint4 rn2 = ZROW(cur.n2), rn3 = ZROW(cur.n3);
    const uint4 rq0 = ZROW(cur.q0), rq1 = ZROW(cur.q1);
    const uint4 rm0 = ZROW(cur.m0), rm1 = ZROW(cur.m1);
    const uint4 rm2 = ZROW(cur.m2), rm3 = ZROW(cur.m3);

    // ---- prefetch next node's indices (consumed next iteration) ----
    const int inext = i + nwaves;
    Idx nxt = cur;
    if (inext < N) nxt = load_idx(pos_idx, neg_idx, dpos_idx, dneg_idx, (unsigned)inext, q);

    // ---- positives: pure accumulation (averaged once at the end) ----
    pa1 = sad16(rp0, zi, sad16(rp1, zi, pa1));
    pa2 = sad16(rq0, zi, sad16(rq1, zi, pa2));

    // ---- negatives: per-neighbor Hamming (integer, exact) ----
    int h0 = (int)sad16(rn0, zi, 0u), h1 = (int)sad16(rn1, zi, 0u);
    int h2 = (int)sad16(rn2, zi, 0u), h3 = (int)sad16(rn3, zi, 0u);
    int g0 = (int)sad16(rm0, zi, 0u), g1 = (int)sad16(rm1, zi, 0u);
    int g2 = (int)sad16(rm2, zi, 0u), g3 = (int)sad16(rm3, zi, 0u);

    h0 += __shfl_xor(h0, 1); h1 += __shfl_xor(h1, 1);
    h2 += __shfl_xor(h2, 1); h3 += __shfl_xor(h3, 1);
    g0 += __shfl_xor(g0, 1); g1 += __shfl_xor(g1, 1);
    g2 += __shfl_xor(g2, 1); g3 += __shfl_xor(g3, 1);
    h0 += __shfl_xor(h0, 2); h1 += __shfl_xor(h1, 2);
    h2 += __shfl_xor(h2, 2); h3 += __shfl_xor(h3, 2);
    g0 += __shfl_xor(g0, 2); g1 += __shfl_xor(g1, 2);
    g2 += __shfl_xor(g2, 2); g3 += __shfl_xor(g3, 2);

    // ---- LSE without max-subtraction: H<=64 so e^H <= 6.2e27 (f32-safe) ----
    float e1 = exp2f((float)h0 * S) + exp2f((float)h1 * S) +
               exp2f((float)h2 * S) + exp2f((float)h3 * S);
    float e2 = exp2f((float)g0 * S) + exp2f((float)g1 * S) +
               exp2f((float)g2 * S) + exp2f((float)g3 * S);
    #pragma unroll
    for (int o = 4; o < 64; o <<= 1) {
      e1 += __shfl_xor(e1, o);
      e2 += __shfl_xor(e2, o);
    }
    l1 += __logf(e1);
    l2 += __logf(e2);

    i = inext;
    cur = nxt;
  }

  // wave-reduce the integer positive accumulators (per-lane distinct)
  int p1s = (int)pa1, p2s = (int)pa2;
  #pragma unroll
  for (int o = 1; o < 64; o <<= 1) { p1s += __shfl_xor(p1s, o); p2s += __shfl_xor(p2s, o); }

  const float pscale = 1.f / (255.f * (float)KPOS);
  const float c1 = l1 - (float)p1s * pscale;   // sum_i (lse - mean_pos)
  const float c2 = l2 - (float)p2s * pscale;

  __shared__ float s1[4], s2[4];
  if (lane == 0) { s1[wid] = c1; s2[wid] = c2; }
  __syncthreads();
  if (threadIdx.x == 0) {
    atomicAdd(out + 0, s1[0] + s1[1] + s1[2] + s1[3]);
    atomicAdd(out + 1, s2[0] + s2[1] + s2[2] + s2[3]);
  }
  #undef ZROW
}

// ---------------- launch ----------------------------------------------------
extern "C" void kernel_launch(void* const* d_in, const int* in_sizes, int n_in,
                              void* d_out, int out_size, void* d_ws, size_t ws_size,
                              hipStream_t stream) {
  const float* P       = (const float*)d_in[0];
  const float* Wd      = (const float*)d_in[1];
  const float* deg     = (const float*)d_in[2];
  const int*   pos_idx = (const int*)d_in[3];
  const int*   neg_idx = (const int*)d_in[4];
  const int*   dpos    = (const int*)d_in[5];
  const int*   dneg    = (const int*)d_in[6];
  float* out = (float*)d_out;

  const int N = in_sizes[2];            // deg_vec has N elements
  uint8_t* Zq = (uint8_t*)d_ws;         // N * 64 bytes = 3.2 MB

  hipMemsetAsync(out, 0, (size_t)out_size * sizeof(float), stream);

  pe_sig_deg_kernel<<<2048, 256, 0, stream>>>(P, Wd, deg, Zq, out, N);
  pe_contrast_kernel<<<2048, 256, 0, stream>>>(Zq, pos_idx, neg_idx, dpos, dneg, out, N);
}

// Round 5
// 101.629 us; speedup vs baseline: 1.0960x; 1.0960x over previous
//
#include <hip/hip_runtime.h>
#include <stdint.h>

#define NDIM 64
#define KPOS 32
#define KNEG 64

// ds_swizzle BitMode patterns: offset = (xor_mask<<10) | (or_mask<<5) | and_mask
#define SWZI(x, pat) __builtin_amdgcn_ds_swizzle((x), (pat))
#define SWZF(x, pat) __int_as_float(__builtin_amdgcn_ds_swizzle(__float_as_int(x), (pat)))

// ---------------- Kernel 1: Zq = u8(sigmoid(P)*255), L_deg = MSE(Z@W_d,deg) -
__global__ __launch_bounds__(256) void pe_sig_deg_kernel(
    const float* __restrict__ P,
    const float* __restrict__ Wd,
    const float* __restrict__ deg,
    uint8_t* __restrict__ Zq,
    float* __restrict__ out,
    int N) {
  const int lane = threadIdx.x & 63;
  const int wid  = threadIdx.x >> 6;
  const int nwaves = (gridDim.x * blockDim.x) >> 6;
  int gw = (blockIdx.x * blockDim.x + threadIdx.x) >> 6;

  const float wd = Wd[lane];
  float acc = 0.f;
  for (int i = gw; i < N; i += nwaves) {
    float p = P[(unsigned)i * NDIM + lane];
    float z = 1.f / (1.f + __expf(-p));
    Zq[((unsigned)i << 6) | lane] = (uint8_t)(z * 255.f + 0.5f);
    float dot = z * wd;                        // exact f32 path for L_deg
    #pragma unroll
    for (int off = 32; off; off >>= 1) dot += __shfl_xor(dot, off);
    float d = dot - deg[i];
    acc += d * d;                              // uniform across lanes
  }
  __shared__ float sacc[4];
  if (lane == 0) sacc[wid] = acc;
  __syncthreads();
  if (threadIdx.x == 0) {
    atomicAdd(out + 2, (sacc[0] + sacc[1] + sacc[2] + sacc[3]) * (1.0f / (float)N));
  }
}

// ---------------- u8 SAD helpers -------------------------------------------
__device__ __forceinline__ unsigned sad16(uint4 a, uint4 b, unsigned acc) {
  acc = __builtin_amdgcn_sad_u8(a.x, b.x, acc);
  acc = __builtin_amdgcn_sad_u8(a.y, b.y, acc);
  acc = __builtin_amdgcn_sad_u8(a.z, b.z, acc);
  acc = __builtin_amdgcn_sad_u8(a.w, b.w, acc);
  return acc;
}

struct Idx { int p0, p1, n0, n1, n2, n3, q0, q1, m0, m1, m2, m3; };

__device__ __forceinline__ Idx load_idx_clamped(
    const int* __restrict__ pos, const int* __restrict__ neg,
    const int* __restrict__ dpos, const int* __restrict__ dneg,
    int i, int N, int q) {
  unsigned u = (unsigned)((i < N) ? i : (N - 1));
  Idx d;
  const int* pr = pos  + u * KPOS;
  const int* nr = neg  + u * KNEG;
  const int* qr = dpos + u * KPOS;
  const int* mr = dneg + u * KNEG;
  d.p0 = pr[q]; d.p1 = pr[16 + q];
  d.n0 = nr[q]; d.n1 = nr[16 + q]; d.n2 = nr[32 + q]; d.n3 = nr[48 + q];
  d.q0 = qr[q]; d.q1 = qr[16 + q];
  d.m0 = mr[q]; d.m1 = mr[16 + q]; d.m2 = mr[32 + q]; d.m3 = mr[48 + q];
  return d;
}

struct Rows { uint4 z, p0, p1, n0, n1, n2, n3, q0, q1, m0, m1, m2, m3; };

__device__ __forceinline__ Rows gather_rows(const uint8_t* __restrict__ Zq,
                                            int i, const Idx& d, unsigned coff) {
  #define ZROW(j) (*(const uint4*)(Zq + ((((unsigned)(j)) << 6) | coff)))
  Rows r;
  r.z  = ZROW(i);
  r.p0 = ZROW(d.p0); r.p1 = ZROW(d.p1);
  r.n0 = ZROW(d.n0); r.n1 = ZROW(d.n1); r.n2 = ZROW(d.n2); r.n3 = ZROW(d.n3);
  r.q0 = ZROW(d.q0); r.q1 = ZROW(d.q1);
  r.m0 = ZROW(d.m0); r.m1 = ZROW(d.m1); r.m2 = ZROW(d.m2); r.m3 = ZROW(d.m3);
  return r;
  #undef ZROW
}

__device__ __forceinline__ void compute_node(const Rows& r,
    float& l1, float& l2, unsigned& pa1, unsigned& pa2) {
  const float S = 1.4426950408889634f / 255.f;   // log2(e)/255

  // positives: pure accumulation (averaged once at the end)
  pa1 = sad16(r.p0, r.z, sad16(r.p1, r.z, pa1));
  pa2 = sad16(r.q0, r.z, sad16(r.q1, r.z, pa2));

  // negatives: per-neighbor Hamming (integer, exact)
  int h0 = (int)sad16(r.n0, r.z, 0u), h1 = (int)sad16(r.n1, r.z, 0u);
  int h2 = (int)sad16(r.n2, r.z, 0u), h3 = (int)sad16(r.n3, r.z, 0u);
  int g0 = (int)sad16(r.m0, r.z, 0u), g1 = (int)sad16(r.m1, r.z, 0u);
  int g2 = (int)sad16(r.m2, r.z, 0u), g3 = (int)sad16(r.m3, r.z, 0u);

  // quad reduce (xor 1, 2) via single-instr ds_swizzle
  h0 += SWZI(h0, 0x041F); h1 += SWZI(h1, 0x041F);
  h2 += SWZI(h2, 0x041F); h3 += SWZI(h3, 0x041F);
  g0 += SWZI(g0, 0x041F); g1 += SWZI(g1, 0x041F);
  g2 += SWZI(g2, 0x041F); g3 += SWZI(g3, 0x041F);
  h0 += SWZI(h0, 0x081F); h1 += SWZI(h1, 0x081F);
  h2 += SWZI(h2, 0x081F); h3 += SWZI(h3, 0x081F);
  g0 += SWZI(g0, 0x081F); g1 += SWZI(g1, 0x081F);
  g2 += SWZI(g2, 0x081F); g3 += SWZI(g3, 0x081F);

  // LSE without max-subtraction: H<=64 so e^H <= 6.2e27 (f32-safe)
  float e1 = exp2f((float)h0 * S) + exp2f((float)h1 * S) +
             exp2f((float)h2 * S) + exp2f((float)h3 * S);
  float e2 = exp2f((float)g0 * S) + exp2f((float)g1 * S) +
             exp2f((float)g2 * S) + exp2f((float)g3 * S);
  // cross-quad butterfly (xor 4, 8, 16 via swizzle; 32 via bpermute)
  e1 += SWZF(e1, 0x101F); e2 += SWZF(e2, 0x101F);
  e1 += SWZF(e1, 0x201F); e2 += SWZF(e2, 0x201F);
  e1 += SWZF(e1, 0x401F); e2 += SWZF(e2, 0x401F);
  e1 += __shfl_xor(e1, 32); e2 += __shfl_xor(e2, 32);

  l1 += __logf(e1);
  l2 += __logf(e2);
}

// ---------------- Kernel 2: both contrast losses (2-node pipelined) --------
__global__ __launch_bounds__(256) void pe_contrast_kernel(
    const uint8_t* __restrict__ Zq,
    const int* __restrict__ pos_idx,
    const int* __restrict__ neg_idx,
    const int* __restrict__ dpos_idx,
    const int* __restrict__ dneg_idx,
    float* __restrict__ out,
    int N) {
  const int lane = threadIdx.x & 63;
  const int q = lane >> 2, c = lane & 3;
  const int wid  = threadIdx.x >> 6;
  const int nw   = (gridDim.x * blockDim.x) >> 6;
  const int gw   = (blockIdx.x * blockDim.x + threadIdx.x) >> 6;
  const unsigned coff = (unsigned)c << 4;

  float l1 = 0.f, l2 = 0.f;
  unsigned pa1 = 0u, pa2 = 0u;

  int i = gw;
  if (i < N) {
    Idx dA = load_idx_clamped(pos_idx, neg_idx, dpos_idx, dneg_idx, i, N, q);
    Rows rA = gather_rows(Zq, i, dA, coff);
    int iB = i + nw;
    Idx dB = load_idx_clamped(pos_idx, neg_idx, dpos_idx, dneg_idx, iB, N, q);

    while (true) {
      // ---- stage B's gathers BEFORE computing A (latency overlap) ----
      const bool vB = (iB < N);                 // wave-uniform
      Rows rB;
      if (vB) rB = gather_rows(Zq, iB, dB, coff);
      const int iC = iB + nw;
      Idx dC = load_idx_clamped(pos_idx, neg_idx, dpos_idx, dneg_idx, iC, N, q);

      compute_node(rA, l1, l2, pa1, pa2);       // overlaps rB loads
      if (!vB) break;

      // ---- stage C's gathers BEFORE computing B ----
      const bool vC = (iC < N);
      Rows rC;
      if (vC) rC = gather_rows(Zq, iC, dC, coff);
      const int iD = iC + nw;
      Idx dD = load_idx_clamped(pos_idx, neg_idx, dpos_idx, dneg_idx, iD, N, q);

      compute_node(rB, l1, l2, pa1, pa2);       // overlaps rC loads
      if (!vC) break;

      rA = rC; dB = dD; iB = iD;                // slide window
    }
  }

  // wave-reduce the integer positive accumulators (per-lane distinct)
  int p1s = (int)pa1, p2s = (int)pa2;
  #pragma unroll
  for (int o = 1; o < 64; o <<= 1) { p1s += __shfl_xor(p1s, o); p2s += __shfl_xor(p2s, o); }

  const float pscale = 1.f / (255.f * (float)KPOS);
  const float c1 = l1 - (float)p1s * pscale;    // sum_i (lse - mean_pos)
  const float c2 = l2 - (float)p2s * pscale;

  __shared__ float s1[4], s2[4];
  if (lane == 0) { s1[wid] = c1; s2[wid] = c2; }
  __syncthreads();
  if (threadIdx.x == 0) {
    atomicAdd(out + 0, s1[0] + s1[1] + s1[2] + s1[3]);
    atomicAdd(out + 1, s2[0] + s2[1] + s2[2] + s2[3]);
  }
}

// ---------------- launch ----------------------------------------------------
extern "C" void kernel_launch(void* const* d_in, const int* in_sizes, int n_in,
                              void* d_out, int out_size, void* d_ws, size_t ws_size,
                              hipStream_t stream) {
  const float* P       = (const float*)d_in[0];
  const float* Wd      = (const float*)d_in[1];
  const float* deg     = (const float*)d_in[2];
  const int*   pos_idx = (const int*)d_in[3];
  const int*   neg_idx = (const int*)d_in[4];
  const int*   dpos    = (const int*)d_in[5];
  const int*   dneg    = (const int*)d_in[6];
  float* out = (float*)d_out;

  const int N = in_sizes[2];            // deg_vec has N elements
  uint8_t* Zq = (uint8_t*)d_ws;         // N * 64 bytes = 3.2 MB

  hipMemsetAsync(out, 0, (size_t)out_size * sizeof(float), stream);

  pe_sig_deg_kernel<<<1024, 256, 0, stream>>>(P, Wd, deg, Zq, out, N);
  pe_contrast_kernel<<<2048, 256, 0, stream>>>(Zq, pos_idx, neg_idx, dpos, dneg, out, N);
}